// Round 1
// baseline (360.085 us; speedup 1.0000x reference)
//
#include <hip/hip_runtime.h>
#include <cstdint>
#include <cstddef>

// SSM layer: y = scan(x @ B^T) @ C^T + D * x
// x: (8,4096,1024) f32; A: (256,) f32; B: (256,1024) f32; C: (1024,256) f32; D: (1024,) f32
// M = 8*4096 = 32768 flattened rows.

typedef __attribute__((ext_vector_type(8))) _Float16 half8;
typedef __attribute__((ext_vector_type(4))) float f32x4;

// ---------------------------------------------------------------------------
// Generic MFMA GEMM:  out[M,N] = A[M,K] * Bm[N,K]^T   (both K-contiguous, f32
// in memory, converted to f16 during LDS staging). If FUSE: out += Dv[col] *
// X[row*N+col].
// Tile: BM=128, BN=128, BK=32. 256 threads = 4 waves, each wave owns a 64x64
// quadrant = 4x4 grid of 16x16x32 MFMA tiles.
// ---------------------------------------------------------------------------
template<int N, int K, bool FUSE>
__global__ __launch_bounds__(256) void gemm_nt(
    const float* __restrict__ A, const float* __restrict__ Bm,
    float* __restrict__ out, const float* __restrict__ Dv,
    const float* __restrict__ X)
{
  constexpr int BM = 128, BN = 128, BK = 32;
  constexpr int LDT = 40;   // padded leading dim (halves): 80B rows, <=2-way bank alias
  __shared__ __align__(16) _Float16 lA[BM * LDT];
  __shared__ __align__(16) _Float16 lB[BN * LDT];

  const int tid  = threadIdx.x;
  const int lane = tid & 63;
  const int wave = tid >> 6;
  const int wm   = (wave & 1) * 64;   // wave quadrant within 128x128 tile
  const int wn   = (wave >> 1) * 64;
  const int quad = lane >> 4;         // 0..3
  const int l16  = lane & 15;

  const long blockM = (long)blockIdx.x * BM;
  const long blockN = (long)blockIdx.y * BN;

  f32x4 acc[4][4];
  #pragma unroll
  for (int i = 0; i < 4; i++)
    #pragma unroll
    for (int j = 0; j < 4; j++)
      acc[i][j] = (f32x4){0.f, 0.f, 0.f, 0.f};

  for (int k0 = 0; k0 < K; k0 += BK) {
    // ---- stage A and B tiles (f32 -> f16) ----
    // 128 rows x 32 k = 512 chunks of 8 elems per tile; thread does 2 chunks each.
    #pragma unroll
    for (int i = 0; i < 2; i++) {
      const int ch  = tid + i * 256;
      const int row = ch >> 2;
      const int kc  = (ch & 3) * 8;

      const float* ga = A + (blockM + row) * (long)K + (k0 + kc);
      float4 a0 = *(const float4*)ga;
      float4 a1 = *(const float4*)(ga + 4);
      half8 pa;
      pa[0] = (_Float16)a0.x; pa[1] = (_Float16)a0.y;
      pa[2] = (_Float16)a0.z; pa[3] = (_Float16)a0.w;
      pa[4] = (_Float16)a1.x; pa[5] = (_Float16)a1.y;
      pa[6] = (_Float16)a1.z; pa[7] = (_Float16)a1.w;
      *(half8*)&lA[row * LDT + kc] = pa;

      const float* gb = Bm + (blockN + row) * (long)K + (k0 + kc);
      float4 b0 = *(const float4*)gb;
      float4 b1 = *(const float4*)(gb + 4);
      half8 pb;
      pb[0] = (_Float16)b0.x; pb[1] = (_Float16)b0.y;
      pb[2] = (_Float16)b0.z; pb[3] = (_Float16)b0.w;
      pb[4] = (_Float16)b1.x; pb[5] = (_Float16)b1.y;
      pb[6] = (_Float16)b1.z; pb[7] = (_Float16)b1.w;
      *(half8*)&lB[row * LDT + kc] = pb;
    }
    __syncthreads();

    // ---- fragments + MFMA ----
    // A frag: lane holds A[m = l16][k = quad*8 + j]; B frag symmetric.
    half8 af[4], bf[4];
    #pragma unroll
    for (int mt = 0; mt < 4; mt++)
      af[mt] = *(const half8*)&lA[(wm + mt * 16 + l16) * LDT + quad * 8];
    #pragma unroll
    for (int nt = 0; nt < 4; nt++)
      bf[nt] = *(const half8*)&lB[(wn + nt * 16 + l16) * LDT + quad * 8];

    #pragma unroll
    for (int mt = 0; mt < 4; mt++)
      #pragma unroll
      for (int nt = 0; nt < 4; nt++)
        acc[mt][nt] = __builtin_amdgcn_mfma_f32_16x16x32_f16(
            af[mt], bf[nt], acc[mt][nt], 0, 0, 0);
    __syncthreads();
  }

  // ---- epilogue: C/D layout col = lane&15, row = quad*4 + reg ----
  #pragma unroll
  for (int mt = 0; mt < 4; mt++) {
    #pragma unroll
    for (int nt = 0; nt < 4; nt++) {
      const long col = blockN + wn + nt * 16 + l16;
      #pragma unroll
      for (int r = 0; r < 4; r++) {
        const long row = blockM + wm + mt * 16 + quad * 4 + r;
        float v = acc[mt][nt][r];
        if (FUSE) v += Dv[col] * X[row * (long)N + col];
        out[row * (long)N + col] = v;
      }
    }
  }
}

// ---------------------------------------------------------------------------
// Chunked scan over time. s=4096 split into 64 chunks of L=64 per batch.
// a_bar is time-invariant: h[t] = local[t] + a^(t_local+1) * carry_chunk.
// ---------------------------------------------------------------------------

// Pass 1: local in-chunk scan, in-place in Bx; chunk-end value to E.
// grid = 512 blocks (blockIdx.x = b*64 + c), 256 threads (n).
__global__ __launch_bounds__(256) void scan_local(
    float* __restrict__ Bx, const float* __restrict__ Ap,
    float* __restrict__ E)
{
  const int n  = threadIdx.x;
  const int bc = blockIdx.x;
  const float al = expf(-expf(Ap[n]));
  size_t base = (size_t)bc * 64 * 256 + n;
  float h = 0.f;
  #pragma unroll 8
  for (int t = 0; t < 64; t++) {
    const size_t i = base + (size_t)t * 256;
    h = al * h + Bx[i];
    Bx[i] = h;
  }
  E[(size_t)bc * 256 + n] = h;
}

// Pass 2: sequential prefix across 64 chunks per (b,n). grid = 8 x 256.
__global__ __launch_bounds__(256) void scan_prefix(
    const float* __restrict__ E, const float* __restrict__ Ap,
    float* __restrict__ carry)
{
  const int n = threadIdx.x;
  const int b = blockIdx.x;
  const float al = expf(-expf(Ap[n]));
  float aL = al;
  #pragma unroll
  for (int i = 0; i < 6; i++) aL *= aL;   // al^64
  float run = 0.f;
  for (int c = 0; c < 64; c++) {
    const size_t idx = ((size_t)b * 64 + c) * 256 + n;
    carry[idx] = run;
    run = aL * run + E[idx];
  }
}

// Pass 3: apply carry in-place: hs[t] = local[t] + al^(t+1) * carry.
__global__ __launch_bounds__(256) void scan_fix(
    float* __restrict__ Bx, const float* __restrict__ Ap,
    const float* __restrict__ carry)
{
  const int n  = threadIdx.x;
  const int bc = blockIdx.x;
  const float al = expf(-expf(Ap[n]));
  const float car = carry[(size_t)bc * 256 + n];
  size_t base = (size_t)bc * 64 * 256 + n;
  float p = al;
  #pragma unroll 8
  for (int t = 0; t < 64; t++) {
    const size_t i = base + (size_t)t * 256;
    Bx[i] = fmaf(p, car, Bx[i]);
    p *= al;
  }
}

// ---------------------------------------------------------------------------
extern "C" void kernel_launch(void* const* d_in, const int* in_sizes, int n_in,
                              void* d_out, int out_size, void* d_ws, size_t ws_size,
                              hipStream_t stream) {
  const float* x  = (const float*)d_in[0];   // (8,4096,1024)
  const float* Ap = (const float*)d_in[1];   // (256,)
  const float* Bp = (const float*)d_in[2];   // (256,1024)
  const float* Cp = (const float*)d_in[3];   // (1024,256)
  const float* Dp = (const float*)d_in[4];   // (1024,)
  float* y = (float*)d_out;                  // (8,4096,1024)

  // workspace: Bx/hs (32768x256 f32, 33.5MB) | E (512x256) | carry (512x256)
  float* Bx    = (float*)d_ws;
  float* E     = Bx + (size_t)32768 * 256;
  float* carry = E + (size_t)512 * 256;

  // 1) Bx = x @ B^T   (M=32768, N=256, K=1024)
  gemm_nt<256, 1024, false><<<dim3(256, 2), 256, 0, stream>>>(
      x, Bp, Bx, nullptr, nullptr);

  // 2) time scan (in place in Bx)
  scan_local <<<512, 256, 0, stream>>>(Bx, Ap, E);
  scan_prefix<<<8,   256, 0, stream>>>(E, Ap, carry);
  scan_fix   <<<512, 256, 0, stream>>>(Bx, Ap, carry);

  // 3) y = hs @ C^T + D * x   (M=32768, N=1024, K=256)
  gemm_nt<1024, 256, true><<<dim3(256, 8), 256, 0, stream>>>(
      Bx, Cp, y, Dp, x);
}